// Round 8
// baseline (315.020 us; speedup 1.0000x reference)
//
#include <hip/hip_runtime.h>

#define N_NODES 50000
#define N_EDGES 800000
#define CH 256
#define NUM_GRAPHS 512
#define LEAKY 0.01f
#define LN_EPS 1e-5f
#define NBLK ((N_NODES + 255) / 256)   // 196

typedef __attribute__((ext_vector_type(4))) float f32x4;
typedef __attribute__((ext_vector_type(2))) float f32x2;
typedef __attribute__((ext_vector_type(8))) short bf16x8;

__device__ __forceinline__ float b2f(unsigned short u) {
    union { unsigned int i; float f; } x; x.i = ((unsigned int)u) << 16; return x.f;
}
__device__ __forceinline__ unsigned short f2b(float f) {  // round-to-nearest-even
    union { float f; unsigned int i; } x; x.f = f;
    unsigned int r = x.i + 0x7fffu + ((x.i >> 16) & 1u);
    return (unsigned short)(r >> 16);
}
__device__ __forceinline__ f32x2 b2f2(unsigned int u) {
    union { unsigned int i; float f; } lo, hi;
    lo.i = u << 16; hi.i = u & 0xffff0000u;
    f32x2 r; r.x = lo.f; r.y = hi.f; return r;
}
__device__ __forceinline__ unsigned int pack2(float a, float b) {
    return (unsigned int)f2b(a) | ((unsigned int)f2b(b) << 16);
}

__global__ void zero_ints(int* __restrict__ p, int n) {
    int i = blockIdx.x * blockDim.x + threadIdx.x;
    if (i < n) p[i] = 0;
}

__global__ void count_deg(const int* __restrict__ dst, int* __restrict__ cnt) {
    int e = blockIdx.x * blockDim.x + threadIdx.x;
    if (e < N_EDGES) atomicAdd(&cnt[dst[e]], 1);
}

__global__ __launch_bounds__(256) void block_reduce(const int* __restrict__ cnt,
                                                    int* __restrict__ bsum,
                                                    float* __restrict__ dinv) {
    __shared__ int s[256];
    int tid = threadIdx.x;
    int i = blockIdx.x * 256 + tid;
    int v = (i < N_NODES) ? cnt[i] : 0;
    if (i < N_NODES) dinv[i] = rsqrtf(1.0f + (float)v);
    s[tid] = v;
    __syncthreads();
    #pragma unroll
    for (int off = 128; off > 0; off >>= 1) {
        if (tid < off) s[tid] += s[tid + off];
        __syncthreads();
    }
    if (tid == 0) bsum[blockIdx.x] = s[0];
}

__global__ __launch_bounds__(256) void scan_bsums(int* __restrict__ bsum) {
    __shared__ int s[256];
    int tid = threadIdx.x;
    int v = (tid < NBLK) ? bsum[tid] : 0;
    s[tid] = v;
    __syncthreads();
    #pragma unroll
    for (int off = 1; off < 256; off <<= 1) {
        int t = (tid >= off) ? s[tid - off] : 0;
        __syncthreads();
        s[tid] += t;
        __syncthreads();
    }
    if (tid < NBLK) bsum[tid] = s[tid] - v;
}

__global__ __launch_bounds__(256) void block_scan(const int* __restrict__ cnt,
                                                  const int* __restrict__ bsum,
                                                  int* __restrict__ rowptr,
                                                  int* __restrict__ cursor) {
    __shared__ int s[256];
    int tid = threadIdx.x;
    int i = blockIdx.x * 256 + tid;
    int v = (i < N_NODES) ? cnt[i] : 0;
    s[tid] = v;
    __syncthreads();
    #pragma unroll
    for (int off = 1; off < 256; off <<= 1) {
        int t = (tid >= off) ? s[tid - off] : 0;
        __syncthreads();
        s[tid] += t;
        __syncthreads();
    }
    if (i < N_NODES) {
        int val = bsum[blockIdx.x] + s[tid] - v;   // exclusive: start of row i
        rowptr[i] = val;
        cursor[i] = val;
        if (i == N_NODES - 1) rowptr[N_NODES] = bsum[blockIdx.x] + s[tid];
    }
}

__global__ void fill_csr(const int* __restrict__ src, const int* __restrict__ dst,
                         int* __restrict__ cursor, int* __restrict__ col) {
    int e = blockIdx.x * blockDim.x + threadIdx.x;
    if (e < N_EDGES) {
        int d = dst[e];
        int p = atomicAdd(&cursor[d], 1);
        col[p] = src[e];
    }
}

__global__ void transpose_w(const float* __restrict__ W, unsigned short* __restrict__ WT) {
    int k = blockIdx.x;
    int n = threadIdx.x;
    WT[n * CH + k] = f2b(W[k * CH + n]);
}

// ---------------- MFMA GEMMs (unchanged)
#define BM 128
#define BN 128
#define BK 64
#define SWZ(row, kb) (((row) * 128 + (kb) * 16) ^ (((row) & 7) << 4))

__global__ __launch_bounds__(256) void gemm_bf16(const unsigned short* __restrict__ A,
                                                 const unsigned short* __restrict__ BT,
                                                 const float* __restrict__ dinv,
                                                 unsigned short* __restrict__ out) {
    __shared__ unsigned short As[BM * BK];
    __shared__ unsigned short Bs[BN * BK];
    const int row0 = blockIdx.x * BM;
    const int col0 = blockIdx.y * BN;
    const int tid = threadIdx.x;
    const int w = tid >> 6, l = tid & 63;
    const int wr = w >> 1, wc = w & 1;
    const int lr = l & 15, lg = l >> 4;

    f32x4 acc[4][4] = {};

    for (int k0 = 0; k0 < CH; k0 += BK) {
        #pragma unroll
        for (int it = 0; it < 4; it++) {
            int cidx = it * 256 + tid;
            int r = cidx >> 3, kb = cidx & 7;
            int grow = row0 + r;
            uint4 va = make_uint4(0u, 0u, 0u, 0u);
            if (grow < N_NODES) va = *(const uint4*)&A[(size_t)grow * CH + k0 + kb * 8];
            *(uint4*)((char*)As + SWZ(r, kb)) = va;
            uint4 vb = *(const uint4*)&BT[(size_t)(col0 + r) * CH + k0 + kb * 8];
            *(uint4*)((char*)Bs + SWZ(r, kb)) = vb;
        }
        __syncthreads();
        #pragma unroll
        for (int ks = 0; ks < 2; ks++) {
            bf16x8 af[4], bfr[4];
            #pragma unroll
            for (int fm = 0; fm < 4; fm++) {
                int r = wr * 64 + fm * 16 + lr;
                af[fm] = *(const bf16x8*)((const char*)As + SWZ(r, ks * 4 + lg));
            }
            #pragma unroll
            for (int fn = 0; fn < 4; fn++) {
                int r = wc * 64 + fn * 16 + lr;
                bfr[fn] = *(const bf16x8*)((const char*)Bs + SWZ(r, ks * 4 + lg));
            }
            #pragma unroll
            for (int fm = 0; fm < 4; fm++)
                #pragma unroll
                for (int fn = 0; fn < 4; fn++)
                    acc[fm][fn] = __builtin_amdgcn_mfma_f32_16x16x32_bf16(af[fm], bfr[fn], acc[fm][fn], 0, 0, 0);
        }
        __syncthreads();
    }
    #pragma unroll
    for (int fm = 0; fm < 4; fm++) {
        #pragma unroll
        for (int r = 0; r < 4; r++) {
            int grow = row0 + wr * 64 + fm * 16 + lg * 4 + r;
            if (grow < N_NODES) {
                float s = dinv[grow];
                #pragma unroll
                for (int fn = 0; fn < 4; fn++) {
                    int gcol = col0 + wc * 64 + fn * 16 + lr;
                    out[(size_t)grow * CH + gcol] = f2b(acc[fm][fn][r] * s);
                }
            }
        }
    }
}

__global__ __launch_bounds__(256) void gemm_f32a(const float* __restrict__ Af,
                                                 const unsigned short* __restrict__ BT,
                                                 const float* __restrict__ dinv,
                                                 unsigned short* __restrict__ out) {
    __shared__ unsigned short As[BM * BK];
    __shared__ unsigned short Bs[BN * BK];
    const int row0 = blockIdx.x * BM;
    const int col0 = blockIdx.y * BN;
    const int tid = threadIdx.x;
    const int w = tid >> 6, l = tid & 63;
    const int wr = w >> 1, wc = w & 1;
    const int lr = l & 15, lg = l >> 4;

    f32x4 acc[4][4] = {};

    for (int k0 = 0; k0 < CH; k0 += BK) {
        #pragma unroll
        for (int it = 0; it < 4; it++) {
            int cidx = it * 256 + tid;
            int r = cidx >> 3, kb = cidx & 7;
            int grow = row0 + r;
            uint4 ua = make_uint4(0u, 0u, 0u, 0u);
            if (grow < N_NODES) {
                const float* ap = &Af[(size_t)grow * CH + k0 + kb * 8];
                float4 v0 = *(const float4*)ap;
                float4 v1 = *(const float4*)(ap + 4);
                ua = make_uint4(pack2(v0.x, v0.y), pack2(v0.z, v0.w),
                                pack2(v1.x, v1.y), pack2(v1.z, v1.w));
            }
            *(uint4*)((char*)As + SWZ(r, kb)) = ua;
            uint4 vb = *(const uint4*)&BT[(size_t)(col0 + r) * CH + k0 + kb * 8];
            *(uint4*)((char*)Bs + SWZ(r, kb)) = vb;
        }
        __syncthreads();
        #pragma unroll
        for (int ks = 0; ks < 2; ks++) {
            bf16x8 af[4], bfr[4];
            #pragma unroll
            for (int fm = 0; fm < 4; fm++) {
                int r = wr * 64 + fm * 16 + lr;
                af[fm] = *(const bf16x8*)((const char*)As + SWZ(r, ks * 4 + lg));
            }
            #pragma unroll
            for (int fn = 0; fn < 4; fn++) {
                int r = wc * 64 + fn * 16 + lr;
                bfr[fn] = *(const bf16x8*)((const char*)Bs + SWZ(r, ks * 4 + lg));
            }
            #pragma unroll
            for (int fm = 0; fm < 4; fm++)
                #pragma unroll
                for (int fn = 0; fn < 4; fn++)
                    acc[fm][fn] = __builtin_amdgcn_mfma_f32_16x16x32_bf16(af[fm], bfr[fn], acc[fm][fn], 0, 0, 0);
        }
        __syncthreads();
    }
    #pragma unroll
    for (int fm = 0; fm < 4; fm++) {
        #pragma unroll
        for (int r = 0; r < 4; r++) {
            int grow = row0 + wr * 64 + fm * 16 + lg * 4 + r;
            if (grow < N_NODES) {
                float s = dinv[grow];
                #pragma unroll
                for (int fn = 0; fn < 4; fn++) {
                    int gcol = col0 + wc * 64 + fn * 16 + lr;
                    out[(size_t)grow * CH + gcol] = f2b(acc[fm][fn][r] * s);
                }
            }
        }
    }
}

// ---------------- gather over in-edges, CHANNEL-HALF per block (XCD L2 partitioning)
// Row layout in uints: 128 uints/node (256 bf16 ch). half h covers uints [h*64, h*64+64).
// Each lane owns 1 uint (2 channels). ROUND-7 BUG WAS: stride 64 / doff half*32+lane.
__global__ __launch_bounds__(256) void gather_half(const unsigned short* __restrict__ h,
                                                   const int* __restrict__ rowptr,
                                                   const int* __restrict__ col,
                                                   const float* __restrict__ dinv,
                                                   const float* __restrict__ bias,
                                                   unsigned short* __restrict__ raw,
                                                   float* __restrict__ stats) {
    const int w = threadIdx.x >> 6, lane = threadIdx.x & 63;
    const unsigned b = blockIdx.x;
    const int half  = (b >> 2) & 1;               // (b&7)>>2
    const int group = (b >> 3) * 4 + (b & 3);     // [0,12500)
    const int d = group * 4 + w;                  // [0,50000)
    const int doff = half * 64 + lane;            // uint index within 128-uint row
    const uint* __restrict__ h1 = (const uint*)h;

    f32x2 acc;
    { uint u = h1[(size_t)d * 128 + doff]; acc = b2f2(u); }   // self loop

    const int e0 = rowptr[d], e1 = rowptr[d + 1];
    for (int base = e0; base < e1; base += 64) {
        int nch = e1 - base; if (nch > 64) nch = 64;
        int cidx = (lane < nch) ? col[base + lane] : 0;
        int j = 0;
        for (; j + 8 <= nch; j += 8) {
            int s0 = __shfl(cidx, j),     s1 = __shfl(cidx, j + 1);
            int s2 = __shfl(cidx, j + 2), s3 = __shfl(cidx, j + 3);
            int s4 = __shfl(cidx, j + 4), s5 = __shfl(cidx, j + 5);
            int s6 = __shfl(cidx, j + 6), s7 = __shfl(cidx, j + 7);
            uint u0 = h1[(size_t)s0 * 128 + doff];
            uint u1 = h1[(size_t)s1 * 128 + doff];
            uint u2 = h1[(size_t)s2 * 128 + doff];
            uint u3 = h1[(size_t)s3 * 128 + doff];
            uint u4 = h1[(size_t)s4 * 128 + doff];
            uint u5 = h1[(size_t)s5 * 128 + doff];
            uint u6 = h1[(size_t)s6 * 128 + doff];
            uint u7 = h1[(size_t)s7 * 128 + doff];
            acc += b2f2(u0) + b2f2(u1) + b2f2(u2) + b2f2(u3);
            acc += b2f2(u4) + b2f2(u5) + b2f2(u6) + b2f2(u7);
        }
        for (; j + 4 <= nch; j += 4) {
            int s0 = __shfl(cidx, j),     s1 = __shfl(cidx, j + 1);
            int s2 = __shfl(cidx, j + 2), s3 = __shfl(cidx, j + 3);
            uint u0 = h1[(size_t)s0 * 128 + doff];
            uint u1 = h1[(size_t)s1 * 128 + doff];
            uint u2 = h1[(size_t)s2 * 128 + doff];
            uint u3 = h1[(size_t)s3 * 128 + doff];
            acc += b2f2(u0) + b2f2(u1) + b2f2(u2) + b2f2(u3);
        }
        for (; j < nch; j++) {
            int s = __shfl(cidx, j);
            uint u = h1[(size_t)s * 128 + doff];
            acc += b2f2(u);
        }
    }
    const float di = dinv[d];
    const float2 bb = *(const float2*)&bias[doff * 2];
    float a0 = acc.x * di + bb.x;
    float a1 = acc.y * di + bb.y;

    float s1 = a0 + a1;
    float s2 = a0 * a0 + a1 * a1;
    #pragma unroll
    for (int off = 32; off > 0; off >>= 1) {
        s1 += __shfl_xor(s1, off);
        s2 += __shfl_xor(s2, off);
    }
    if (lane == 0) {
        stats[d * 4 + half * 2 + 0] = s1;
        stats[d * 4 + half * 2 + 1] = s2;
    }
    ((uint*)raw)[(size_t)d * 128 + doff] = pack2(a0, a1);
}

// ---------------- LN finalize (streaming): y = LN(raw)*w+b, leaky
__global__ __launch_bounds__(256) void ln_final(const unsigned short* __restrict__ raw,
                                                const float* __restrict__ stats,
                                                const float* __restrict__ lnw,
                                                const float* __restrict__ lnb,
                                                unsigned short* __restrict__ out) {
    const int w = threadIdx.x >> 6, lane = threadIdx.x & 63;
    const int d = blockIdx.x * 4 + w;
    const int c4 = lane * 4;
    uint2 u = ((const uint2*)raw)[(size_t)d * 64 + lane];
    f32x2 a01 = b2f2(u.x), a23 = b2f2(u.y);
    float4 st = *(const float4*)&stats[d * 4];
    const float mu = (st.x + st.z) * (1.0f / CH);
    const float var = (st.y + st.w) * (1.0f / CH) - mu * mu;
    const float rstd = rsqrtf(var + LN_EPS);
    float4 wv = *(const float4*)&lnw[c4];
    float4 bv = *(const float4*)&lnb[c4];
    float y0 = (a01.x - mu) * rstd * wv.x + bv.x;
    float y1 = (a01.y - mu) * rstd * wv.y + bv.y;
    float y2 = (a23.x - mu) * rstd * wv.z + bv.z;
    float y3 = (a23.y - mu) * rstd * wv.w + bv.w;
    y0 = (y0 >= 0.f) ? y0 : LEAKY * y0;
    y1 = (y1 >= 0.f) ? y1 : LEAKY * y1;
    y2 = (y2 >= 0.f) ? y2 : LEAKY * y2;
    y3 = (y3 >= 0.f) ? y3 : LEAKY * y3;
    *(ushort4*)&out[(size_t)d * CH + c4] = make_ushort4(f2b(y0), f2b(y1), f2b(y2), f2b(y3));
}

// ---------------- pool with fused LN finalize for layer 2
__global__ __launch_bounds__(256) void pool_ln(const unsigned short* __restrict__ raw,
                                               const float* __restrict__ stats,
                                               const float* __restrict__ lnw,
                                               const float* __restrict__ lnb,
                                               const int* __restrict__ batch,
                                               float* __restrict__ out) {
    const int g = blockIdx.x;
    const int w = threadIdx.x >> 6, lane = threadIdx.x & 63;
    const int c4 = lane * 4;
    int lo = 0, hi = N_NODES;
    while (lo < hi) { int mid = (lo + hi) >> 1; if (batch[mid] < g) lo = mid + 1; else hi = mid; }
    const int start = lo;
    hi = N_NODES;
    while (lo < hi) { int mid = (lo + hi) >> 1; if (batch[mid] < g + 1) lo = mid + 1; else hi = mid; }
    const int end = lo;

    float4 wv = *(const float4*)&lnw[c4];
    float4 bv = *(const float4*)&lnb[c4];
    float a0 = 0.f, a1 = 0.f, a2 = 0.f, a3 = 0.f;
    for (int n = start + w; n < end; n += 4) {
        uint2 u = ((const uint2*)raw)[(size_t)n * 64 + lane];
        f32x2 r01 = b2f2(u.x), r23 = b2f2(u.y);
        float4 st = *(const float4*)&stats[n * 4];
        const float mu = (st.x + st.z) * (1.0f / CH);
        const float var = (st.y + st.w) * (1.0f / CH) - mu * mu;
        const float rstd = rsqrtf(var + LN_EPS);
        float y0 = (r01.x - mu) * rstd * wv.x + bv.x;
        float y1 = (r01.y - mu) * rstd * wv.y + bv.y;
        float y2 = (r23.x - mu) * rstd * wv.z + bv.z;
        float y3 = (r23.y - mu) * rstd * wv.w + bv.w;
        a0 += (y0 >= 0.f) ? y0 : LEAKY * y0;
        a1 += (y1 >= 0.f) ? y1 : LEAKY * y1;
        a2 += (y2 >= 0.f) ? y2 : LEAKY * y2;
        a3 += (y3 >= 0.f) ? y3 : LEAKY * y3;
    }
    __shared__ float4 red[4][64];
    red[w][lane] = make_float4(a0, a1, a2, a3);
    __syncthreads();
    if (w == 0) {
        float4 t0 = red[0][lane], t1 = red[1][lane], t2 = red[2][lane], t3 = red[3][lane];
        const float inv = (end > start) ? 1.0f / (float)(end - start) : 0.0f;
        float4 o = make_float4((t0.x + t1.x + t2.x + t3.x) * inv,
                               (t0.y + t1.y + t2.y + t3.y) * inv,
                               (t0.z + t1.z + t2.z + t3.z) * inv,
                               (t0.w + t1.w + t2.w + t3.w) * inv);
        *(float4*)&out[(size_t)g * CH + lane * 4] = o;
    }
}

static inline size_t align256(size_t x) { return (x + 255) & ~(size_t)255; }

extern "C" void kernel_launch(void* const* d_in, const int* in_sizes, int n_in,
                              void* d_out, int out_size, void* d_ws, size_t ws_size,
                              hipStream_t stream) {
    const float* x    = (const float*)d_in[0];
    const int*   edge = (const int*)d_in[1];
    const int*   batch= (const int*)d_in[2];
    const float* W1   = (const float*)d_in[3];
    const float* b1   = (const float*)d_in[4];
    const float* ln1w = (const float*)d_in[5];
    const float* ln1b = (const float*)d_in[6];
    const float* W2   = (const float*)d_in[7];
    const float* b2   = (const float*)d_in[8];
    const float* ln2w = (const float*)d_in[9];
    const float* ln2b = (const float*)d_in[10];

    const int* src = edge;
    const int* dst = edge + N_EDGES;

    char* p = (char*)d_ws;
    int* cnt    = (int*)p;  p += align256(N_NODES * 4);
    int* cursor = (int*)p;  p += align256(N_NODES * 4);
    int* rowptr = (int*)p;  p += align256((N_NODES + 1) * 4);
    int* bsum   = (int*)p;  p += align256(NBLK * 4);
    float* dinv = (float*)p; p += align256(N_NODES * 4);
    float* stats= (float*)p; p += align256((size_t)N_NODES * 4 * 4);
    int* col    = (int*)p;  p += align256(N_EDGES * 4);
    unsigned short* wt1 = (unsigned short*)p; p += align256(CH * CH * 2);
    unsigned short* wt2 = (unsigned short*)p; p += align256(CH * CH * 2);
    unsigned short* bufA = (unsigned short*)p; p += align256((size_t)N_NODES * CH * 2);  // h
    unsigned short* bufB = (unsigned short*)p; p += align256((size_t)N_NODES * CH * 2);  // y
    unsigned short* bufC = (unsigned short*)p;                                            // raw agg

    zero_ints<<<(N_NODES + 255) / 256, 256, 0, stream>>>(cnt, N_NODES);
    count_deg<<<(N_EDGES + 255) / 256, 256, 0, stream>>>(dst, cnt);
    block_reduce<<<NBLK, 256, 0, stream>>>(cnt, bsum, dinv);
    scan_bsums<<<1, 256, 0, stream>>>(bsum);
    block_scan<<<NBLK, 256, 0, stream>>>(cnt, bsum, rowptr, cursor);
    fill_csr<<<(N_EDGES + 255) / 256, 256, 0, stream>>>(src, dst, cursor, col);

    transpose_w<<<CH, CH, 0, stream>>>(W1, wt1);
    transpose_w<<<CH, CH, 0, stream>>>(W2, wt2);

    dim3 ggrid((N_NODES + BM - 1) / BM, CH / BN);
    const int gblocks = (N_NODES / 4) * 2;   // 25000: (node-group x half) oct-mapped

    gemm_f32a<<<ggrid, 256, 0, stream>>>(x, wt1, dinv, bufA);
    gather_half<<<gblocks, 256, 0, stream>>>(bufA, rowptr, col, dinv, b1, bufC, stats);
    ln_final<<<N_NODES / 4, 256, 0, stream>>>(bufC, stats, ln1w, ln1b, bufB);
    gemm_bf16<<<ggrid, 256, 0, stream>>>(bufB, wt2, dinv, bufA);
    gather_half<<<gblocks, 256, 0, stream>>>(bufA, rowptr, col, dinv, b2, bufC, stats);
    pool_ln<<<NUM_GRAPHS, 256, 0, stream>>>(bufC, stats, ln2w, ln2b, batch, (float*)d_out);
}

// Round 9
// 293.043 us; speedup vs baseline: 1.0750x; 1.0750x over previous
//
#include <hip/hip_runtime.h>

#define N_NODES 50000
#define N_EDGES 800000
#define CH 256
#define NUM_GRAPHS 512
#define LEAKY 0.01f
#define LN_EPS 1e-5f
#define NBLK ((N_NODES + 255) / 256)   // 196

typedef __attribute__((ext_vector_type(4))) float f32x4;
typedef __attribute__((ext_vector_type(2))) float f32x2;
typedef __attribute__((ext_vector_type(8))) short bf16x8;

__device__ __forceinline__ float b2f(unsigned short u) {
    union { unsigned int i; float f; } x; x.i = ((unsigned int)u) << 16; return x.f;
}
__device__ __forceinline__ unsigned short f2b(float f) {  // round-to-nearest-even
    union { float f; unsigned int i; } x; x.f = f;
    unsigned int r = x.i + 0x7fffu + ((x.i >> 16) & 1u);
    return (unsigned short)(r >> 16);
}
__device__ __forceinline__ f32x2 b2f2(unsigned int u) {
    union { unsigned int i; float f; } lo, hi;
    lo.i = u << 16; hi.i = u & 0xffff0000u;
    f32x2 r; r.x = lo.f; r.y = hi.f; return r;
}
__device__ __forceinline__ unsigned int pack2(float a, float b) {
    return (unsigned int)f2b(a) | ((unsigned int)f2b(b) << 16);
}
// async global->LDS, 16B per lane; LDS dest is wave-uniform base + lane*16
__device__ __forceinline__ void gload16(const void* g, void* l) {
    __builtin_amdgcn_global_load_lds((const __attribute__((address_space(1))) unsigned int*)g,
                                     (__attribute__((address_space(3))) unsigned int*)l, 16, 0, 0);
}

__global__ void zero_ints(int* __restrict__ p, int n) {
    int i = blockIdx.x * blockDim.x + threadIdx.x;
    if (i < n) p[i] = 0;
}

__global__ void count_deg(const int* __restrict__ dst, int* __restrict__ cnt) {
    int e = blockIdx.x * blockDim.x + threadIdx.x;
    if (e < N_EDGES) atomicAdd(&cnt[dst[e]], 1);
}

__global__ __launch_bounds__(256) void block_reduce(const int* __restrict__ cnt,
                                                    int* __restrict__ bsum,
                                                    float* __restrict__ dinv) {
    __shared__ int s[256];
    int tid = threadIdx.x;
    int i = blockIdx.x * 256 + tid;
    int v = (i < N_NODES) ? cnt[i] : 0;
    if (i < N_NODES) dinv[i] = rsqrtf(1.0f + (float)v);
    s[tid] = v;
    __syncthreads();
    #pragma unroll
    for (int off = 128; off > 0; off >>= 1) {
        if (tid < off) s[tid] += s[tid + off];
        __syncthreads();
    }
    if (tid == 0) bsum[blockIdx.x] = s[0];
}

__global__ __launch_bounds__(256) void scan_bsums(int* __restrict__ bsum) {
    __shared__ int s[256];
    int tid = threadIdx.x;
    int v = (tid < NBLK) ? bsum[tid] : 0;
    s[tid] = v;
    __syncthreads();
    #pragma unroll
    for (int off = 1; off < 256; off <<= 1) {
        int t = (tid >= off) ? s[tid - off] : 0;
        __syncthreads();
        s[tid] += t;
        __syncthreads();
    }
    if (tid < NBLK) bsum[tid] = s[tid] - v;
}

__global__ __launch_bounds__(256) void block_scan(const int* __restrict__ cnt,
                                                  const int* __restrict__ bsum,
                                                  int* __restrict__ rowptr,
                                                  int* __restrict__ cursor) {
    __shared__ int s[256];
    int tid = threadIdx.x;
    int i = blockIdx.x * 256 + tid;
    int v = (i < N_NODES) ? cnt[i] : 0;
    s[tid] = v;
    __syncthreads();
    #pragma unroll
    for (int off = 1; off < 256; off <<= 1) {
        int t = (tid >= off) ? s[tid - off] : 0;
        __syncthreads();
        s[tid] += t;
        __syncthreads();
    }
    if (i < N_NODES) {
        int val = bsum[blockIdx.x] + s[tid] - v;   // exclusive: start of row i
        rowptr[i] = val;
        cursor[i] = val;
        if (i == N_NODES - 1) rowptr[N_NODES] = bsum[blockIdx.x] + s[tid];
    }
}

__global__ void fill_csr(const int* __restrict__ src, const int* __restrict__ dst,
                         int* __restrict__ cursor, int* __restrict__ col) {
    int e = blockIdx.x * blockDim.x + threadIdx.x;
    if (e < N_EDGES) {
        int d = dst[e];
        int p = atomicAdd(&cursor[d], 1);
        col[p] = src[e];
    }
}

// both W1 and W2 in one launch: grid 512, blocks [0,256)->W1, [256,512)->W2
__global__ void transpose_w2(const float* __restrict__ W1f, const float* __restrict__ W2f,
                             unsigned short* __restrict__ WT1, unsigned short* __restrict__ WT2) {
    int k = blockIdx.x & 255;
    const float* W = (blockIdx.x >> 8) ? W2f : W1f;
    unsigned short* WT = (blockIdx.x >> 8) ? WT2 : WT1;
    int n = threadIdx.x;
    WT[n * CH + k] = f2b(W[k * CH + n]);
}

// ---------------- MFMA GEMMs
#define BM 128
#define BN 128
#define BK 64
// reader-side swizzle; LDS content written so that SWZ-read returns tile[r][kb]
#define SWZ(row, kb) (((row) * 128 + (kb) * 16) ^ (((row) & 7) << 4))

// layer 2: A bf16 (ws buffer, padded) -> both tiles staged via global_load_lds.
// linear LDS slot (r, kb') must hold global element (r, kb'^(r&7)) so SWZ-read matches.
__global__ __launch_bounds__(256) void gemm_bf16(const unsigned short* __restrict__ A,
                                                 const unsigned short* __restrict__ BT,
                                                 const float* __restrict__ dinv,
                                                 unsigned short* __restrict__ out) {
    __shared__ unsigned short As[BM * BK];
    __shared__ unsigned short Bs[BN * BK];
    const int row0 = blockIdx.x * BM;
    const int col0 = blockIdx.y * BN;
    const int tid = threadIdx.x;
    const int w = tid >> 6, l = tid & 63;
    const int wr = w >> 1, wc = w & 1;
    const int lr = l & 15, lg = l >> 4;

    // staging geometry: wave w, iter it -> rows [(w*4+it)*8, +8); lane l -> r=R+(l>>3), kb'=l&7
    const int sr = l >> 3;          // 0..7 row within 8-row stripe
    const int kbp = l & 7;          // linear col chunk

    f32x4 acc[4][4] = {};

    for (int k0 = 0; k0 < CH; k0 += BK) {
        #pragma unroll
        for (int it = 0; it < 4; it++) {
            const int R = (w * 4 + it) * 8;
            const int r = R + sr;
            const int kb = kbp ^ (r & 7);                 // pre-swizzled source column
            gload16(&A[(size_t)(row0 + r) * CH + k0 + kb * 8], (char*)As + R * 128);
            gload16(&BT[(size_t)(col0 + r) * CH + k0 + kb * 8], (char*)Bs + R * 128);
        }
        __syncthreads();   // drains vmcnt -> LDS tiles complete
        #pragma unroll
        for (int ks = 0; ks < 2; ks++) {
            bf16x8 af[4], bfr[4];
            #pragma unroll
            for (int fm = 0; fm < 4; fm++) {
                int r = wr * 64 + fm * 16 + lr;
                af[fm] = *(const bf16x8*)((const char*)As + SWZ(r, ks * 4 + lg));
            }
            #pragma unroll
            for (int fn = 0; fn < 4; fn++) {
                int r = wc * 64 + fn * 16 + lr;
                bfr[fn] = *(const bf16x8*)((const char*)Bs + SWZ(r, ks * 4 + lg));
            }
            #pragma unroll
            for (int fm = 0; fm < 4; fm++)
                #pragma unroll
                for (int fn = 0; fn < 4; fn++)
                    acc[fm][fn] = __builtin_amdgcn_mfma_f32_16x16x32_bf16(af[fm], bfr[fn], acc[fm][fn], 0, 0, 0);
        }
        __syncthreads();
    }
    #pragma unroll
    for (int fm = 0; fm < 4; fm++) {
        #pragma unroll
        for (int r = 0; r < 4; r++) {
            int grow = row0 + wr * 64 + fm * 16 + lg * 4 + r;
            if (grow < N_NODES) {
                float s = dinv[grow];
                #pragma unroll
                for (int fn = 0; fn < 4; fn++) {
                    int gcol = col0 + wc * 64 + fn * 16 + lr;
                    out[(size_t)grow * CH + gcol] = f2b(acc[fm][fn][r] * s);
                }
            }
        }
    }
}

// layer 1: A f32 (harness x, bounds-guarded reg staging + cvt); B via global_load_lds
__global__ __launch_bounds__(256) void gemm_f32a(const float* __restrict__ Af,
                                                 const unsigned short* __restrict__ BT,
                                                 const float* __restrict__ dinv,
                                                 unsigned short* __restrict__ out) {
    __shared__ unsigned short As[BM * BK];
    __shared__ unsigned short Bs[BN * BK];
    const int row0 = blockIdx.x * BM;
    const int col0 = blockIdx.y * BN;
    const int tid = threadIdx.x;
    const int w = tid >> 6, l = tid & 63;
    const int wr = w >> 1, wc = w & 1;
    const int lr = l & 15, lg = l >> 4;
    const int sr = l >> 3, kbp = l & 7;

    f32x4 acc[4][4] = {};

    for (int k0 = 0; k0 < CH; k0 += BK) {
        // B tile async
        #pragma unroll
        for (int it = 0; it < 4; it++) {
            const int R = (w * 4 + it) * 8;
            const int r = R + sr;
            const int kb = kbp ^ (r & 7);
            gload16(&BT[(size_t)(col0 + r) * CH + k0 + kb * 8], (char*)Bs + R * 128);
        }
        // A tile: reg staging with f32->bf16 cvt, swizzled ds_write
        #pragma unroll
        for (int it = 0; it < 4; it++) {
            int cidx = it * 256 + tid;
            int r = cidx >> 3, kb = cidx & 7;
            int grow = row0 + r;
            uint4 ua = make_uint4(0u, 0u, 0u, 0u);
            if (grow < N_NODES) {
                const float* ap = &Af[(size_t)grow * CH + k0 + kb * 8];
                float4 v0 = *(const float4*)ap;
                float4 v1 = *(const float4*)(ap + 4);
                ua = make_uint4(pack2(v0.x, v0.y), pack2(v0.z, v0.w),
                                pack2(v1.x, v1.y), pack2(v1.z, v1.w));
            }
            *(uint4*)((char*)As + SWZ(r, kb)) = ua;
        }
        __syncthreads();
        #pragma unroll
        for (int ks = 0; ks < 2; ks++) {
            bf16x8 af[4], bfr[4];
            #pragma unroll
            for (int fm = 0; fm < 4; fm++) {
                int r = wr * 64 + fm * 16 + lr;
                af[fm] = *(const bf16x8*)((const char*)As + SWZ(r, ks * 4 + lg));
            }
            #pragma unroll
            for (int fn = 0; fn < 4; fn++) {
                int r = wc * 64 + fn * 16 + lr;
                bfr[fn] = *(const bf16x8*)((const char*)Bs + SWZ(r, ks * 4 + lg));
            }
            #pragma unroll
            for (int fm = 0; fm < 4; fm++)
                #pragma unroll
                for (int fn = 0; fn < 4; fn++)
                    acc[fm][fn] = __builtin_amdgcn_mfma_f32_16x16x32_bf16(af[fm], bfr[fn], acc[fm][fn], 0, 0, 0);
        }
        __syncthreads();
    }
    #pragma unroll
    for (int fm = 0; fm < 4; fm++) {
        #pragma unroll
        for (int r = 0; r < 4; r++) {
            int grow = row0 + wr * 64 + fm * 16 + lg * 4 + r;
            if (grow < N_NODES) {
                float s = dinv[grow];
                #pragma unroll
                for (int fn = 0; fn < 4; fn++) {
                    int gcol = col0 + wc * 64 + fn * 16 + lr;
                    out[(size_t)grow * CH + gcol] = f2b(acc[fm][fn][r] * s);
                }
            }
        }
    }
}

// ---------------- aggregation + LN + LeakyReLU, one WAVE per node (round-5/6 verified form)
__global__ __launch_bounds__(256) void agg_ln_bf16(const unsigned short* __restrict__ h,
                                                   const int* __restrict__ rowptr,
                                                   const int* __restrict__ col,
                                                   const float* __restrict__ dinv,
                                                   const float* __restrict__ bias,
                                                   const float* __restrict__ lnw,
                                                   const float* __restrict__ lnb,
                                                   unsigned short* __restrict__ out) {
    const int w = threadIdx.x >> 6, lane = threadIdx.x & 63;
    const int d = blockIdx.x * 4 + w;
    if (d >= N_NODES) return;   // wave-uniform exit
    const int c4 = lane * 4;
    const uint2* __restrict__ h2 = (const uint2*)h;   // h2[node*64 + lane] = 4 channels

    f32x2 acc01, acc23;
    {
        uint2 u = h2[(unsigned)(d * 64 + lane)];      // self loop
        acc01 = b2f2(u.x); acc23 = b2f2(u.y);
    }

    const int e0 = rowptr[d], e1 = rowptr[d + 1];
    for (int base = e0; base < e1; base += 64) {
        int nch = e1 - base; if (nch > 64) nch = 64;
        int cidx = (lane < nch) ? col[base + lane] : 0;
        int j = 0;
        for (; j + 8 <= nch; j += 8) {
            int s0 = __shfl(cidx, j),     s1 = __shfl(cidx, j + 1);
            int s2 = __shfl(cidx, j + 2), s3 = __shfl(cidx, j + 3);
            int s4 = __shfl(cidx, j + 4), s5 = __shfl(cidx, j + 5);
            int s6 = __shfl(cidx, j + 6), s7 = __shfl(cidx, j + 7);
            uint2 u0 = h2[(unsigned)(s0 * 64 + lane)];
            uint2 u1 = h2[(unsigned)(s1 * 64 + lane)];
            uint2 u2 = h2[(unsigned)(s2 * 64 + lane)];
            uint2 u3 = h2[(unsigned)(s3 * 64 + lane)];
            uint2 u4 = h2[(unsigned)(s4 * 64 + lane)];
            uint2 u5 = h2[(unsigned)(s5 * 64 + lane)];
            uint2 u6 = h2[(unsigned)(s6 * 64 + lane)];
            uint2 u7 = h2[(unsigned)(s7 * 64 + lane)];
            acc01 += b2f2(u0.x) + b2f2(u1.x) + b2f2(u2.x) + b2f2(u3.x);
            acc23 += b2f2(u0.y) + b2f2(u1.y) + b2f2(u2.y) + b2f2(u3.y);
            acc01 += b2f2(u4.x) + b2f2(u5.x) + b2f2(u6.x) + b2f2(u7.x);
            acc23 += b2f2(u4.y) + b2f2(u5.y) + b2f2(u6.y) + b2f2(u7.y);
        }
        for (; j + 4 <= nch; j += 4) {
            int s0 = __shfl(cidx, j),     s1 = __shfl(cidx, j + 1);
            int s2 = __shfl(cidx, j + 2), s3 = __shfl(cidx, j + 3);
            uint2 u0 = h2[(unsigned)(s0 * 64 + lane)];
            uint2 u1 = h2[(unsigned)(s1 * 64 + lane)];
            uint2 u2 = h2[(unsigned)(s2 * 64 + lane)];
            uint2 u3 = h2[(unsigned)(s3 * 64 + lane)];
            acc01 += b2f2(u0.x) + b2f2(u1.x) + b2f2(u2.x) + b2f2(u3.x);
            acc23 += b2f2(u0.y) + b2f2(u1.y) + b2f2(u2.y) + b2f2(u3.y);
        }
        for (; j < nch; j++) {
            int s = __shfl(cidx, j);
            uint2 u = h2[(unsigned)(s * 64 + lane)];
            acc01 += b2f2(u.x); acc23 += b2f2(u.y);
        }
    }
    float a0 = acc01.x, a1 = acc01.y, a2 = acc23.x, a3 = acc23.y;
    const float di = dinv[d];
    float4 bb = *(const float4*)&bias[c4];
    a0 = a0 * di + bb.x; a1 = a1 * di + bb.y; a2 = a2 * di + bb.z; a3 = a3 * di + bb.w;

    float s1 = a0 + a1 + a2 + a3;
    float s2 = a0 * a0 + a1 * a1 + a2 * a2 + a3 * a3;
    #pragma unroll
    for (int off = 32; off > 0; off >>= 1) {
        s1 += __shfl_xor(s1, off);
        s2 += __shfl_xor(s2, off);
    }
    const float mu = s1 * (1.0f / CH);
    const float rstd = rsqrtf(s2 * (1.0f / CH) - mu * mu + LN_EPS);
    float4 wv = *(const float4*)&lnw[c4];
    float4 bv = *(const float4*)&lnb[c4];
    float y0 = (a0 - mu) * rstd * wv.x + bv.x;
    float y1 = (a1 - mu) * rstd * wv.y + bv.y;
    float y2 = (a2 - mu) * rstd * wv.z + bv.z;
    float y3 = (a3 - mu) * rstd * wv.w + bv.w;
    y0 = (y0 >= 0.f) ? y0 : LEAKY * y0;
    y1 = (y1 >= 0.f) ? y1 : LEAKY * y1;
    y2 = (y2 >= 0.f) ? y2 : LEAKY * y2;
    y3 = (y3 >= 0.f) ? y3 : LEAKY * y3;
    *(ushort4*)&out[(size_t)d * CH + c4] = make_ushort4(f2b(y0), f2b(y1), f2b(y2), f2b(y3));
}

// 4 waves per graph, node range split across waves, LDS cross-wave reduce
__global__ __launch_bounds__(256) void pool_mean_bf16(const unsigned short* __restrict__ feat,
                                                      const int* __restrict__ batch,
                                                      float* __restrict__ out) {
    const int g = blockIdx.x;
    const int w = threadIdx.x >> 6, lane = threadIdx.x & 63;
    int lo = 0, hi = N_NODES;
    while (lo < hi) { int mid = (lo + hi) >> 1; if (batch[mid] < g) lo = mid + 1; else hi = mid; }
    const int start = lo;
    hi = N_NODES;
    while (lo < hi) { int mid = (lo + hi) >> 1; if (batch[mid] < g + 1) lo = mid + 1; else hi = mid; }
    const int end = lo;

    float a0 = 0.f, a1 = 0.f, a2 = 0.f, a3 = 0.f;
    for (int n = start + w; n < end; n += 4) {
        ushort4 u = *(const ushort4*)&feat[(size_t)n * CH + lane * 4];
        a0 += b2f(u.x); a1 += b2f(u.y); a2 += b2f(u.z); a3 += b2f(u.w);
    }
    __shared__ float4 red[4][64];
    red[w][lane] = make_float4(a0, a1, a2, a3);
    __syncthreads();
    if (w == 0) {
        float4 t0 = red[0][lane], t1 = red[1][lane], t2 = red[2][lane], t3 = red[3][lane];
        const float inv = (end > start) ? 1.0f / (float)(end - start) : 0.0f;
        float4 o = make_float4((t0.x + t1.x + t2.x + t3.x) * inv,
                               (t0.y + t1.y + t2.y + t3.y) * inv,
                               (t0.z + t1.z + t2.z + t3.z) * inv,
                               (t0.w + t1.w + t2.w + t3.w) * inv);
        *(float4*)&out[(size_t)g * CH + lane * 4] = o;
    }
}

static inline size_t align256(size_t x) { return (x + 255) & ~(size_t)255; }

extern "C" void kernel_launch(void* const* d_in, const int* in_sizes, int n_in,
                              void* d_out, int out_size, void* d_ws, size_t ws_size,
                              hipStream_t stream) {
    const float* x    = (const float*)d_in[0];
    const int*   edge = (const int*)d_in[1];
    const int*   batch= (const int*)d_in[2];
    const float* W1   = (const float*)d_in[3];
    const float* b1   = (const float*)d_in[4];
    const float* ln1w = (const float*)d_in[5];
    const float* ln1b = (const float*)d_in[6];
    const float* W2   = (const float*)d_in[7];
    const float* b2   = (const float*)d_in[8];
    const float* ln2w = (const float*)d_in[9];
    const float* ln2b = (const float*)d_in[10];

    const int* src = edge;
    const int* dst = edge + N_EDGES;

    char* p = (char*)d_ws;
    int* cnt    = (int*)p;  p += align256(N_NODES * 4);
    int* cursor = (int*)p;  p += align256(N_NODES * 4);
    int* rowptr = (int*)p;  p += align256((N_NODES + 1) * 4);
    int* bsum   = (int*)p;  p += align256(NBLK * 4);
    float* dinv = (float*)p; p += align256(N_NODES * 4);
    int* col    = (int*)p;  p += align256(N_EDGES * 4);
    unsigned short* wt1 = (unsigned short*)p; p += align256(CH * CH * 2);
    unsigned short* wt2 = (unsigned short*)p; p += align256(CH * CH * 2);
    unsigned short* bufA = (unsigned short*)p; p += align256((size_t)N_NODES * CH * 2);  // h
    unsigned short* bufB = (unsigned short*)p; p += align256((size_t)N_NODES * CH * 2);  // y
    p += 32768;  // OOB-read pad for gemm_bf16's unguarded global_load_lds tail rows

    zero_ints<<<(N_NODES + 255) / 256, 256, 0, stream>>>(cnt, N_NODES);
    count_deg<<<(N_EDGES + 255) / 256, 256, 0, stream>>>(dst, cnt);
    block_reduce<<<NBLK, 256, 0, stream>>>(cnt, bsum, dinv);
    scan_bsums<<<1, 256, 0, stream>>>(bsum);
    block_scan<<<NBLK, 256, 0, stream>>>(cnt, bsum, rowptr, cursor);
    fill_csr<<<(N_EDGES + 255) / 256, 256, 0, stream>>>(src, dst, cursor, col);
    transpose_w2<<<2 * CH, CH, 0, stream>>>(W1, W2, wt1, wt2);

    dim3 ggrid((N_NODES + BM - 1) / BM, CH / BN);
    gemm_f32a<<<ggrid, 256, 0, stream>>>(x, wt1, dinv, bufA);
    agg_ln_bf16<<<(N_NODES + 3) / 4, 256, 0, stream>>>(bufA, rowptr, col, dinv, b1, ln1w, ln1b, bufB);
    gemm_bf16<<<ggrid, 256, 0, stream>>>(bufB, wt2, dinv, bufA);
    agg_ln_bf16<<<(N_NODES + 3) / 4, 256, 0, stream>>>(bufA, rowptr, col, dinv, b2, ln2w, ln2b, bufB);
    pool_mean_bf16<<<NUM_GRAPHS, 256, 0, stream>>>(bufB, batch, (float*)d_out);
}